// Round 6
// baseline (181.568 us; speedup 1.0000x reference)
//
#include <hip/hip_runtime.h>

// B=16, C=256, HEADS=4, d=64, N=W*H=1024
constexpr int Bb  = 16;
constexpr int Cch = 256;
constexpr int NH  = 4;
constexpr int Dh  = 64;
constexpr int Nn  = 1024;

typedef _Float16 f16;
typedef __attribute__((ext_vector_type(8))) _Float16 f16x8;
typedef __attribute__((ext_vector_type(4))) _Float16 f16x4;
typedef __attribute__((ext_vector_type(4))) float    f32x4;

// ---------------------------------------------------------------------------
// ROUND 6 (= ROUND 5 resubmitted after infra failure):
// prep shrunk to rel_t only (xtrans + W-cast fused into gemm_qkv).
// rel_t[h][n][d] = f16(rel_h[h][d][n&31] + rel_w[h][d][n>>5])
// grid = 256, block = 256, 4 elems/thread (f16x4 store).
// ---------------------------------------------------------------------------
__global__ __launch_bounds__(256) void prep_rel(
    const float* __restrict__ rel_h, const float* __restrict__ rel_w,
    f16* __restrict__ rel_t)
{
    const int idx0 = (blockIdx.x * 256 + threadIdx.x) * 4;  // 262144 total
    const int d0 = idx0 & 63;
    const int n  = (idx0 >> 6) & (Nn - 1);
    const int h  = idx0 >> 16;
    f16x4 w;
    #pragma unroll
    for (int u = 0; u < 4; u++) {
        const int hd = h * 64 + d0 + u;
        w[u] = (f16)(rel_h[hd * 32 + (n & 31)] + rel_w[hd * 32 + (n >> 5)]);
    }
    *(f16x4*)&rel_t[idx0] = w;
}

// ---------------------------------------------------------------------------
// QKV projection GEMM, fp16 MFMA.
// Stages directly from fp32 x and W (prep fusion).
//  - W chunk [128 o][32 c]: f32 loads, in-register f16 cast, direct Wt write
//    (no transpose needed: W is [o][c], Wt is [o][c]).
//  - x chunk [32 c][128 n]: f32 loads -> LDS scratch T[32][132] (padded,
//    conflict-free) -> transposed f16 Xt[n][c] writes.
//  - Removes the 100 MB HBM round trip (xt/Wh buffers deleted).
//  - MFMA / fragment-read / epilogue structure unchanged (ST=40).
// grid = (8, 6, 16), block = 256.  LDS = 10+10+16.5 = 37.4 KB.
// ---------------------------------------------------------------------------
__global__ __launch_bounds__(256) void gemm_qkv(
    const float* __restrict__ x,
    const float* __restrict__ Wq, const float* __restrict__ Wk,
    const float* __restrict__ Wv,
    const float* __restrict__ bq, const float* __restrict__ bk,
    const float* __restrict__ bv,
    f16* __restrict__ qt, f16* __restrict__ kt, f16* __restrict__ vb)
{
    const int bx   = blockIdx.x;
    const int y    = blockIdx.y;
    const int b    = blockIdx.z;
    const int p    = y >> 1;
    const int half = y & 1;

    constexpr int ST = 40;
    __shared__ f16   Wt[128 * ST];    // [o 128][c 32]
    __shared__ f16   Xt[128 * ST];    // [n 128][c 32]
    __shared__ float T [32 * 132];    // [c 32][n 128 +pad4]

    const int t    = threadIdx.x;
    const int wave = t >> 6;
    const int lane = t & 63;
    const int l16  = lane & 15;
    const int quad = lane >> 4;
    const int wm   = wave >> 1;
    const int wsd  = wave & 1;

    const float* Wsel = (p == 0) ? Wq : (p == 1) ? Wk : Wv;

    f32x4 acc[4][4];
    #pragma unroll
    for (int mi = 0; mi < 4; mi++)
        #pragma unroll
        for (int ni = 0; ni < 4; ni++) acc[mi][ni] = (f32x4){0.f, 0.f, 0.f, 0.f};

    for (int c0 = 0; c0 < 256; c0 += 32) {
        // ---- global loads (f32) to regs ----
        float4 wreg[4], xreg[4];
        #pragma unroll
        for (int rep = 0; rep < 4; rep++) {
            const int e  = t + rep * 256;
            const int r  = e >> 3;          // o row 0..127
            const int c4 = e & 7;           // float4 within 32-c chunk
            wreg[rep] = *(const float4*)
                &Wsel[(size_t)(half * 128 + r) * 256 + c0 + c4 * 4];
            const int cc = e >> 5;          // c row 0..31
            const int n4 = e & 31;          // float4 within 128-n chunk
            xreg[rep] = *(const float4*)
                &x[((size_t)b * Cch + c0 + cc) * Nn + bx * 128 + n4 * 4];
        }
        __syncthreads();   // prior MFMA reads of Wt/Xt (and T reuse) complete

        // ---- S1: Wt (cast) + T (raw f32) ----
        #pragma unroll
        for (int rep = 0; rep < 4; rep++) {
            const int e  = t + rep * 256;
            const int r  = e >> 3;
            const int c4 = e & 7;
            f16x4 wv;
            wv.x = (f16)wreg[rep].x; wv.y = (f16)wreg[rep].y;
            wv.z = (f16)wreg[rep].z; wv.w = (f16)wreg[rep].w;
            *(f16x4*)&Wt[r * ST + c4 * 4] = wv;
            const int cc = e >> 5;
            const int n4 = e & 31;
            *(float4*)&T[cc * 132 + n4 * 4] = xreg[rep];
        }
        __syncthreads();

        // ---- S2: Xt[n][c] from T (transpose + cast) ----
        #pragma unroll
        for (int rep = 0; rep < 2; rep++) {
            const int e  = t + rep * 256;
            const int nn = e & 127;
            const int c8 = e >> 7;          // 0..3 over 2 reps of 256
            f16x8 xv;
            #pragma unroll
            for (int u = 0; u < 8; u++)
                xv[u] = (f16)T[(c8 * 8 + u) * 132 + nn];
            *(f16x8*)&Xt[nn * ST + c8 * 8] = xv;
        }
        __syncthreads();

        // ---- MFMA (unchanged) ----
        const f16* tf = (p < 2) ? Wt : Xt;
        const f16* ts = (p < 2) ? Xt : Wt;
        f16x8 af[4], bf[4];
        #pragma unroll
        for (int mi = 0; mi < 4; mi++)
            af[mi] = *(const f16x8*)&tf[(wm * 64 + mi * 16 + l16) * ST + quad * 8];
        #pragma unroll
        for (int ni = 0; ni < 4; ni++)
            bf[ni] = *(const f16x8*)&ts[(wsd * 64 + ni * 16 + l16) * ST + quad * 8];
        #pragma unroll
        for (int mi = 0; mi < 4; mi++)
            #pragma unroll
            for (int ni = 0; ni < 4; ni++)
                acc[mi][ni] = __builtin_amdgcn_mfma_f32_16x16x32_f16(
                    af[mi], bf[ni], acc[mi][ni], 0, 0, 0);
    }

    if (p < 2) {
        f16* yt = (p == 0) ? qt : kt;
        const float* bg = (p == 0) ? bq : bk;
        #pragma unroll
        for (int mi = 0; mi < 4; mi++) {
            const int o_in = half * 128 + wm * 64 + mi * 16 + quad * 4;
            const float4 b4 = *(const float4*)&bg[o_in];
            const int h = o_in >> 6;
            const int d = o_in & 63;
            #pragma unroll
            for (int ni = 0; ni < 4; ni++) {
                const int n = bx * 128 + wsd * 64 + ni * 16 + l16;
                f16x4 w;
                w.x = (f16)(acc[mi][ni][0] + b4.x);
                w.y = (f16)(acc[mi][ni][1] + b4.y);
                w.z = (f16)(acc[mi][ni][2] + b4.z);
                w.w = (f16)(acc[mi][ni][3] + b4.w);
                *(f16x4*)&yt[(((size_t)b * NH + h) * Nn + n) * Dh + d] = w;
            }
        }
    } else {
        #pragma unroll
        for (int ni = 0; ni < 4; ni++) {
            const int c  = half * 128 + wsd * 64 + ni * 16 + l16;
            const float bs = bv[c];
            #pragma unroll
            for (int mi = 0; mi < 4; mi++) {
                const int n = bx * 128 + wm * 64 + mi * 16 + quad * 4;
                f16x4 w;
                w.x = (f16)(acc[mi][ni][0] + bs);
                w.y = (f16)(acc[mi][ni][1] + bs);
                w.z = (f16)(acc[mi][ni][2] + bs);
                w.w = (f16)(acc[mi][ni][3] + bs);
                *(f16x4*)&vb[((size_t)b * Cch + c) * Nn + n] = w;
            }
        }
    }
}

// ---------------------------------------------------------------------------
// Flash attention, fp16 MFMA, XOR-swizzled LDS. Unchanged from Round 4
// (passing): XCD-bijective mapping (FETCH 102->13.8 MB), no setprio.
// grid = (512), block = 512.
// ---------------------------------------------------------------------------
__global__ __launch_bounds__(512, 4) void attn_mfma(
    const f16* __restrict__ qt, const f16* __restrict__ kt,
    const f16* __restrict__ relt, const f16* __restrict__ vb,
    float* __restrict__ out)
{
    // XCD-bijective decode: all blocks with the same bh share an XCD
    const int bid = blockIdx.x;
    const int bh  = bid & 63;         // b*4 + h
    const int i0  = (bid >> 6) * 128;
    const int h   = bh & 3;
    const int b   = bh >> 2;

    const f16* qtb = qt  + (size_t)bh * Nn * Dh;            // [n][64]
    const f16* ktb = kt  + (size_t)bh * Nn * Dh;            // [n][64]
    const f16* rlt = relt + (size_t)h * Nn * Dh;            // [n][64]
    const f16* vbb = vb  + (size_t)(b * Cch + h * Dh) * Nn; // [d][1024]

    // XOR-swizzled tiles: elem(row, col) at row*W + ((col>>3 ^ (row&7))<<3) + (col&7)
    __shared__ f16 Qa_s[128 * 128];  // 32 KB  [i][128: q|rel]
    __shared__ f16 Ka_s[64 * 128];   // 16 KB  [j][128: k|q]
    __shared__ f16 v_s [64 * 64];    //  8 KB  [d][j]
    __shared__ f16 Pt_s[128 * 64];   // 16 KB  [i][j]

    const int t    = threadIdx.x;
    const int wave = t >> 6;         // 0..7
    const int lane = t & 63;
    const int l16  = lane & 15;
    const int quad = lane >> 4;

    // ---- stage Qa = [q | rel]: 128 rows x 128 f16, swizzled ----
    #pragma unroll
    for (int rep = 0; rep < 4; rep++) {
        const int e   = t + rep * 512;
        const int row = e >> 4;
        const int c8  = e & 15;
        const f16* src = (c8 < 8)
            ? &qtb[(size_t)(i0 + row) * Dh + c8 * 8]
            : &rlt[(size_t)(i0 + row) * Dh + (c8 - 8) * 8];
        *(f16x8*)&Qa_s[(row << 7) + ((c8 ^ (row & 7)) << 3)] = *(const f16x8*)src;
    }
    __syncthreads();

    // ---- hoist Qa A-fragments (j-invariant): 1 m-subtile x 4 k-slices ----
    f16x8 af[4];
    {
        const int row = wave * 16 + l16;
        #pragma unroll
        for (int k = 0; k < 4; k++)
            af[k] = *(const f16x8*)
                &Qa_s[(row << 7) + ((((k << 2) + quad) ^ (row & 7)) << 3)];
    }

    f16x8 ones;
    #pragma unroll
    for (int u = 0; u < 8; u++) ones[u] = (f16)1.0f;

    f32x4 Of[4], Ol;
    float m_r[4];
    Ol = (f32x4){0.f, 0.f, 0.f, 0.f};
    #pragma unroll
    for (int ds = 0; ds < 4; ds++) Of[ds] = (f32x4){0.f, 0.f, 0.f, 0.f};
    #pragma unroll
    for (int r = 0; r < 4; r++) m_r[r] = -1e30f;

    for (int j0 = 0; j0 < Nn; j0 += 64) {
        // global -> regs
        f16x8 kreg[2], vreg;
        #pragma unroll
        for (int rep = 0; rep < 2; rep++) {
            const int e   = t + rep * 512;
            const int row = e >> 4;
            const int c8  = e & 15;
            const f16* src = (c8 < 8)
                ? &ktb[(size_t)(j0 + row) * Dh + c8 * 8]
                : &qtb[(size_t)(j0 + row) * Dh + (c8 - 8) * 8];
            kreg[rep] = *(const f16x8*)src;
        }
        {
            const int row = t >> 3;
            const int c8  = t & 7;
            vreg = *(const f16x8*)&vbb[(size_t)row * Nn + j0 + c8 * 8];
        }

        __syncthreads();   // prior iter's Ka/v reads complete
        #pragma unroll
        for (int rep = 0; rep < 2; rep++) {
            const int e   = t + rep * 512;
            const int row = e >> 4;
            const int c8  = e & 15;
            *(f16x8*)&Ka_s[(row << 7) + ((c8 ^ (row & 7)) << 3)] = kreg[rep];
        }
        {
            const int row = t >> 3;
            const int c8  = t & 7;
            *(f16x8*)&v_s[(row << 6) + ((c8 ^ (row & 7)) << 3)] = vreg;
        }
        __syncthreads();

        // ---- S = Qa·Ka^T : 16 rows x 64 cols, K=128 ----
        f32x4 Sf[4];
        #pragma unroll
        for (int js = 0; js < 4; js++) Sf[js] = (f32x4){0.f, 0.f, 0.f, 0.f};
        #pragma unroll
        for (int k = 0; k < 4; k++) {
            f16x8 bb[4];
            #pragma unroll
            for (int js = 0; js < 4; js++) {
                const int row = js * 16 + l16;
                bb[js] = *(const f16x8*)
                    &Ka_s[(row << 7) + ((((k << 2) + quad) ^ (row & 7)) << 3)];
            }
            #pragma unroll
            for (int js = 0; js < 4; js++)
                Sf[js] = __builtin_amdgcn_mfma_f32_16x16x32_f16(
                    af[k], bb[js], Sf[js], 0, 0, 0);
        }

        // ---- online softmax (max tree only; sums via MFMA ones) ----
        #pragma unroll
        for (int r = 0; r < 4; r++) {
            float tm = fmaxf(fmaxf(Sf[0][r], Sf[1][r]),
                             fmaxf(Sf[2][r], Sf[3][r]));
            tm = fmaxf(tm, __shfl_xor(tm, 1));
            tm = fmaxf(tm, __shfl_xor(tm, 2));
            tm = fmaxf(tm, __shfl_xor(tm, 4));
            tm = fmaxf(tm, __shfl_xor(tm, 8));
            const float mnew  = fmaxf(m_r[r], tm);
            const float alpha = __expf(m_r[r] - mnew);
            m_r[r] = mnew;

            const int row = wave * 16 + quad * 4 + r;
            const int rx  = row & 7;
            #pragma unroll
            for (int js = 0; js < 4; js++) {
                const float p = __expf(Sf[js][r] - mnew);
                const int col = js * 16 + l16;
                Pt_s[(row << 6) + (((col >> 3) ^ rx) << 3) + (col & 7)] = (f16)p;
            }
            #pragma unroll
            for (int ds = 0; ds < 4; ds++) Of[ds][r] *= alpha;
            Ol[r] *= alpha;
        }
        // Pt rows are wave-private: in-wave LDS ordering, no barrier

        // ---- O += P·V^T (K=64); l += P·1 ----
        #pragma unroll
        for (int ks = 0; ks < 2; ks++) {
            const int prow = wave * 16 + l16;
            f16x8 pa = *(const f16x8*)
                &Pt_s[(prow << 6) + ((((ks << 2) + quad) ^ (prow & 7)) << 3)];
            #pragma unroll
            for (int ds = 0; ds < 4; ds++) {
                const int vrow = ds * 16 + l16;
                f16x8 vv = *(const f16x8*)
                    &v_s[(vrow << 6) + ((((ks << 2) + quad) ^ (vrow & 7)) << 3)];
                Of[ds] = __builtin_amdgcn_mfma_f32_16x16x32_f16(
                    pa, vv, Of[ds], 0, 0, 0);
            }
            Ol = __builtin_amdgcn_mfma_f32_16x16x32_f16(
                pa, ones, Ol, 0, 0, 0);
        }
    }

    // ---- epilogue ----
    #pragma unroll
    for (int r = 0; r < 4; r++) {
        const float inv = 1.0f / Ol[r];
        const int i = i0 + wave * 16 + quad * 4 + r;
        #pragma unroll
        for (int ds = 0; ds < 4; ds++) {
            const int d = ds * 16 + l16;
            out[((size_t)(b * Cch + h * Dh + d)) * Nn + i] = Of[ds][r] * inv;
        }
    }
}

// ---------------------------------------------------------------------------
extern "C" void kernel_launch(void* const* d_in, const int* in_sizes, int n_in,
                              void* d_out, int out_size, void* d_ws, size_t ws_size,
                              hipStream_t stream)
{
    const float* x     = (const float*)d_in[0];
    const float* Wq    = (const float*)d_in[1];
    const float* bq    = (const float*)d_in[2];
    const float* Wk    = (const float*)d_in[3];
    const float* bk    = (const float*)d_in[4];
    const float* Wv    = (const float*)d_in[5];
    const float* bv    = (const float*)d_in[6];
    const float* rel_h = (const float*)d_in[7];
    const float* rel_w = (const float*)d_in[8];

    f16* ws = (f16*)d_ws;
    const size_t SZQ = (size_t)Bb * NH * Nn * Dh;    // 4 Mi elems
    f16* qt   = ws;                                  // 8 MB
    f16* kt   = ws + SZQ;                            // 8 MB
    f16* vbuf = ws + 2 * SZQ;                        // 8 MB
    f16* relt = ws + 3 * SZQ;                        // 0.5 MB

    prep_rel<<<dim3(256), 256, 0, stream>>>(rel_h, rel_w, relt);
    gemm_qkv<<<dim3(Nn / 128, 6, Bb), 256, 0, stream>>>(
        x, Wq, Wk, Wv, bq, bk, bv, qt, kt, vbuf);
    attn_mfma<<<dim3(512), 512, 0, stream>>>(
        qt, kt, relt, vbuf, (float*)d_out);
}

// Round 7
// 165.816 us; speedup vs baseline: 1.0950x; 1.0950x over previous
//
#include <hip/hip_runtime.h>

// B=16, C=256, HEADS=4, d=64, N=W*H=1024
constexpr int Bb  = 16;
constexpr int Cch = 256;
constexpr int NH  = 4;
constexpr int Dh  = 64;
constexpr int Nn  = 1024;

typedef _Float16 f16;
typedef __attribute__((ext_vector_type(8))) _Float16 f16x8;
typedef __attribute__((ext_vector_type(4))) _Float16 f16x4;
typedef __attribute__((ext_vector_type(4))) float    f32x4;

// ---------------------------------------------------------------------------
// QKV projection GEMM, fp16 MFMA.
// ROUND 7: 2-barrier staging (R6's 3-barrier T-scratch path removed).
//  - W chunk [128 o][32 c]: float4 loads, in-register f16 cast, direct Wt.
//  - x chunk: loaded DIRECTLY TRANSPOSED from global: per-lane 8 dword loads
//    down the c-dim; consecutive lanes read consecutive n addresses ->
//    coalesced 256 B/instruction. Cast in-register, write Xt[n][c] straight.
//  - LDS 20 KB (T scratch deleted), 2 barriers/step (was 3).
//  - x-panel sharing: the 6 y-blocks of one (b,bx) have equal linear-id mod 8
//    -> same XCD -> x fetched ~once from HBM (~64 MB total).
// grid = (8, 6, 16), block = 256.
// ---------------------------------------------------------------------------
__global__ __launch_bounds__(256) void gemm_qkv(
    const float* __restrict__ x,
    const float* __restrict__ Wq, const float* __restrict__ Wk,
    const float* __restrict__ Wv,
    const float* __restrict__ bq, const float* __restrict__ bk,
    const float* __restrict__ bv,
    f16* __restrict__ qt, f16* __restrict__ kt, f16* __restrict__ vb)
{
    const int bx   = blockIdx.x;
    const int y    = blockIdx.y;
    const int b    = blockIdx.z;
    const int p    = y >> 1;
    const int half = y & 1;

    constexpr int ST = 40;
    __shared__ f16 Wt[128 * ST];    // [o 128][c 32]
    __shared__ f16 Xt[128 * ST];    // [n 128][c 32]

    const int t    = threadIdx.x;
    const int wave = t >> 6;
    const int lane = t & 63;
    const int l16  = lane & 15;
    const int quad = lane >> 4;
    const int wm   = wave >> 1;
    const int wsd  = wave & 1;

    const float* Wsel = (p == 0) ? Wq : (p == 1) ? Wk : Wv;

    f32x4 acc[4][4];
    #pragma unroll
    for (int mi = 0; mi < 4; mi++)
        #pragma unroll
        for (int ni = 0; ni < 4; ni++) acc[mi][ni] = (f32x4){0.f, 0.f, 0.f, 0.f};

    for (int c0 = 0; c0 < 256; c0 += 32) {
        // ---- global -> regs ----
        float4 wreg[4];
        float  xcol[2][8];
        #pragma unroll
        for (int rep = 0; rep < 4; rep++) {
            const int e  = t + rep * 256;
            const int r  = e >> 3;          // o row 0..127
            const int c4 = e & 7;           // float4 within 32-c chunk
            wreg[rep] = *(const float4*)
                &Wsel[(size_t)(half * 128 + r) * 256 + c0 + c4 * 4];
        }
        #pragma unroll
        for (int rep = 0; rep < 2; rep++) {
            const int e  = t + rep * 256;
            const int nn = e & 127;         // n within 128-tile
            const int c8 = e >> 7;          // 8-c group 0..3
            #pragma unroll
            for (int u = 0; u < 8; u++)
                xcol[rep][u] = x[((size_t)b * Cch + c0 + c8 * 8 + u) * Nn
                                 + bx * 128 + nn];
        }
        __syncthreads();   // prior MFMA reads of Wt/Xt complete

        // ---- regs -> LDS (cast) ----
        #pragma unroll
        for (int rep = 0; rep < 4; rep++) {
            const int e  = t + rep * 256;
            const int r  = e >> 3;
            const int c4 = e & 7;
            f16x4 wv;
            wv.x = (f16)wreg[rep].x; wv.y = (f16)wreg[rep].y;
            wv.z = (f16)wreg[rep].z; wv.w = (f16)wreg[rep].w;
            *(f16x4*)&Wt[r * ST + c4 * 4] = wv;
        }
        #pragma unroll
        for (int rep = 0; rep < 2; rep++) {
            const int e  = t + rep * 256;
            const int nn = e & 127;
            const int c8 = e >> 7;
            f16x8 xv;
            #pragma unroll
            for (int u = 0; u < 8; u++) xv[u] = (f16)xcol[rep][u];
            *(f16x8*)&Xt[nn * ST + c8 * 8] = xv;
        }
        __syncthreads();

        // ---- MFMA (unchanged) ----
        const f16* tf = (p < 2) ? Wt : Xt;
        const f16* ts = (p < 2) ? Xt : Wt;
        f16x8 af[4], bf[4];
        #pragma unroll
        for (int mi = 0; mi < 4; mi++)
            af[mi] = *(const f16x8*)&tf[(wm * 64 + mi * 16 + l16) * ST + quad * 8];
        #pragma unroll
        for (int ni = 0; ni < 4; ni++)
            bf[ni] = *(const f16x8*)&ts[(wsd * 64 + ni * 16 + l16) * ST + quad * 8];
        #pragma unroll
        for (int mi = 0; mi < 4; mi++)
            #pragma unroll
            for (int ni = 0; ni < 4; ni++)
                acc[mi][ni] = __builtin_amdgcn_mfma_f32_16x16x32_f16(
                    af[mi], bf[ni], acc[mi][ni], 0, 0, 0);
    }

    if (p < 2) {
        f16* yt = (p == 0) ? qt : kt;
        const float* bg = (p == 0) ? bq : bk;
        #pragma unroll
        for (int mi = 0; mi < 4; mi++) {
            const int o_in = half * 128 + wm * 64 + mi * 16 + quad * 4;
            const float4 b4 = *(const float4*)&bg[o_in];
            const int h = o_in >> 6;
            const int d = o_in & 63;
            #pragma unroll
            for (int ni = 0; ni < 4; ni++) {
                const int n = bx * 128 + wsd * 64 + ni * 16 + l16;
                f16x4 w;
                w.x = (f16)(acc[mi][ni][0] + b4.x);
                w.y = (f16)(acc[mi][ni][1] + b4.y);
                w.z = (f16)(acc[mi][ni][2] + b4.z);
                w.w = (f16)(acc[mi][ni][3] + b4.w);
                *(f16x4*)&yt[(((size_t)b * NH + h) * Nn + n) * Dh + d] = w;
            }
        }
    } else {
        #pragma unroll
        for (int ni = 0; ni < 4; ni++) {
            const int c  = half * 128 + wsd * 64 + ni * 16 + l16;
            const float bs = bv[c];
            #pragma unroll
            for (int mi = 0; mi < 4; mi++) {
                const int n = bx * 128 + wm * 64 + mi * 16 + quad * 4;
                f16x4 w;
                w.x = (f16)(acc[mi][ni][0] + bs);
                w.y = (f16)(acc[mi][ni][1] + bs);
                w.z = (f16)(acc[mi][ni][2] + bs);
                w.w = (f16)(acc[mi][ni][3] + bs);
                *(f16x4*)&vb[((size_t)b * Cch + c) * Nn + n] = w;
            }
        }
    }
}

// ---------------------------------------------------------------------------
// Flash attention, fp16 MFMA, XOR-swizzled LDS.
// ROUND 7: rel computed INLINE during one-time Qa staging (prep_rel kernel
// deleted; rel_h/rel_w are 32 KB f32 tables, L2-hot, XCD-shared).
// Otherwise identical to the R4/R6 passing version: XCD-bijective mapping
// (FETCH 102->13.8 MB), no setprio.
// grid = (512), block = 512.
// ---------------------------------------------------------------------------
__global__ __launch_bounds__(512, 4) void attn_mfma(
    const f16* __restrict__ qt, const f16* __restrict__ kt,
    const float* __restrict__ rel_h, const float* __restrict__ rel_w,
    const f16* __restrict__ vb, float* __restrict__ out)
{
    // XCD-bijective decode: all blocks with the same bh share an XCD
    const int bid = blockIdx.x;
    const int bh  = bid & 63;         // b*4 + h
    const int i0  = (bid >> 6) * 128;
    const int h   = bh & 3;
    const int b   = bh >> 2;

    const f16* qtb = qt  + (size_t)bh * Nn * Dh;            // [n][64]
    const f16* ktb = kt  + (size_t)bh * Nn * Dh;            // [n][64]
    const f16* vbb = vb  + (size_t)(b * Cch + h * Dh) * Nn; // [d][1024]

    // XOR-swizzled tiles: elem(row, col) at row*W + ((col>>3 ^ (row&7))<<3) + (col&7)
    __shared__ f16 Qa_s[128 * 128];  // 32 KB  [i][128: q|rel]
    __shared__ f16 Ka_s[64 * 128];   // 16 KB  [j][128: k|q]
    __shared__ f16 v_s [64 * 64];    //  8 KB  [d][j]
    __shared__ f16 Pt_s[128 * 64];   // 16 KB  [i][j]

    const int t    = threadIdx.x;
    const int wave = t >> 6;         // 0..7
    const int lane = t & 63;
    const int l16  = lane & 15;
    const int quad = lane >> 4;

    // ---- stage Qa = [q | rel]: 128 rows x 128 f16, swizzled; rel inline ----
    #pragma unroll
    for (int rep = 0; rep < 4; rep++) {
        const int e   = t + rep * 512;
        const int row = e >> 4;
        const int c8  = e & 15;
        f16x8 val;
        if (c8 < 8) {
            val = *(const f16x8*)&qtb[(size_t)(i0 + row) * Dh + c8 * 8];
        } else {
            const int n  = i0 + row;
            const int d0 = (c8 - 8) * 8;
            #pragma unroll
            for (int u = 0; u < 8; u++) {
                const int hd = h * 64 + d0 + u;
                val[u] = (f16)(rel_h[hd * 32 + (n & 31)] +
                               rel_w[hd * 32 + (n >> 5)]);
            }
        }
        *(f16x8*)&Qa_s[(row << 7) + ((c8 ^ (row & 7)) << 3)] = val;
    }
    __syncthreads();

    // ---- hoist Qa A-fragments (j-invariant): 1 m-subtile x 4 k-slices ----
    f16x8 af[4];
    {
        const int row = wave * 16 + l16;
        #pragma unroll
        for (int k = 0; k < 4; k++)
            af[k] = *(const f16x8*)
                &Qa_s[(row << 7) + ((((k << 2) + quad) ^ (row & 7)) << 3)];
    }

    f16x8 ones;
    #pragma unroll
    for (int u = 0; u < 8; u++) ones[u] = (f16)1.0f;

    f32x4 Of[4], Ol;
    float m_r[4];
    Ol = (f32x4){0.f, 0.f, 0.f, 0.f};
    #pragma unroll
    for (int ds = 0; ds < 4; ds++) Of[ds] = (f32x4){0.f, 0.f, 0.f, 0.f};
    #pragma unroll
    for (int r = 0; r < 4; r++) m_r[r] = -1e30f;

    for (int j0 = 0; j0 < Nn; j0 += 64) {
        // global -> regs
        f16x8 kreg[2], vreg;
        #pragma unroll
        for (int rep = 0; rep < 2; rep++) {
            const int e   = t + rep * 512;
            const int row = e >> 4;
            const int c8  = e & 15;
            const f16* src = (c8 < 8)
                ? &ktb[(size_t)(j0 + row) * Dh + c8 * 8]
                : &qtb[(size_t)(j0 + row) * Dh + (c8 - 8) * 8];
            kreg[rep] = *(const f16x8*)src;
        }
        {
            const int row = t >> 3;
            const int c8  = t & 7;
            vreg = *(const f16x8*)&vbb[(size_t)row * Nn + j0 + c8 * 8];
        }

        __syncthreads();   // prior iter's Ka/v reads complete
        #pragma unroll
        for (int rep = 0; rep < 2; rep++) {
            const int e   = t + rep * 512;
            const int row = e >> 4;
            const int c8  = e & 15;
            *(f16x8*)&Ka_s[(row << 7) + ((c8 ^ (row & 7)) << 3)] = kreg[rep];
        }
        {
            const int row = t >> 3;
            const int c8  = t & 7;
            *(f16x8*)&v_s[(row << 6) + ((c8 ^ (row & 7)) << 3)] = vreg;
        }
        __syncthreads();

        // ---- S = Qa·Ka^T : 16 rows x 64 cols, K=128 ----
        f32x4 Sf[4];
        #pragma unroll
        for (int js = 0; js < 4; js++) Sf[js] = (f32x4){0.f, 0.f, 0.f, 0.f};
        #pragma unroll
        for (int k = 0; k < 4; k++) {
            f16x8 bb[4];
            #pragma unroll
            for (int js = 0; js < 4; js++) {
                const int row = js * 16 + l16;
                bb[js] = *(const f16x8*)
                    &Ka_s[(row << 7) + ((((k << 2) + quad) ^ (row & 7)) << 3)];
            }
            #pragma unroll
            for (int js = 0; js < 4; js++)
                Sf[js] = __builtin_amdgcn_mfma_f32_16x16x32_f16(
                    af[k], bb[js], Sf[js], 0, 0, 0);
        }

        // ---- online softmax (max tree only; sums via MFMA ones) ----
        #pragma unroll
        for (int r = 0; r < 4; r++) {
            float tm = fmaxf(fmaxf(Sf[0][r], Sf[1][r]),
                             fmaxf(Sf[2][r], Sf[3][r]));
            tm = fmaxf(tm, __shfl_xor(tm, 1));
            tm = fmaxf(tm, __shfl_xor(tm, 2));
            tm = fmaxf(tm, __shfl_xor(tm, 4));
            tm = fmaxf(tm, __shfl_xor(tm, 8));
            const float mnew  = fmaxf(m_r[r], tm);
            const float alpha = __expf(m_r[r] - mnew);
            m_r[r] = mnew;

            const int row = wave * 16 + quad * 4 + r;
            const int rx  = row & 7;
            #pragma unroll
            for (int js = 0; js < 4; js++) {
                const float p = __expf(Sf[js][r] - mnew);
                const int col = js * 16 + l16;
                Pt_s[(row << 6) + (((col >> 3) ^ rx) << 3) + (col & 7)] = (f16)p;
            }
            #pragma unroll
            for (int ds = 0; ds < 4; ds++) Of[ds][r] *= alpha;
            Ol[r] *= alpha;
        }
        // Pt rows are wave-private: in-wave LDS ordering, no barrier

        // ---- O += P·V^T (K=64); l += P·1 ----
        #pragma unroll
        for (int ks = 0; ks < 2; ks++) {
            const int prow = wave * 16 + l16;
            f16x8 pa = *(const f16x8*)
                &Pt_s[(prow << 6) + ((((ks << 2) + quad) ^ (prow & 7)) << 3)];
            #pragma unroll
            for (int ds = 0; ds < 4; ds++) {
                const int vrow = ds * 16 + l16;
                f16x8 vv = *(const f16x8*)
                    &v_s[(vrow << 6) + ((((ks << 2) + quad) ^ (vrow & 7)) << 3)];
                Of[ds] = __builtin_amdgcn_mfma_f32_16x16x32_f16(
                    pa, vv, Of[ds], 0, 0, 0);
            }
            Ol = __builtin_amdgcn_mfma_f32_16x16x32_f16(
                pa, ones, Ol, 0, 0, 0);
        }
    }

    // ---- epilogue ----
    #pragma unroll
    for (int r = 0; r < 4; r++) {
        const float inv = 1.0f / Ol[r];
        const int i = i0 + wave * 16 + quad * 4 + r;
        #pragma unroll
        for (int ds = 0; ds < 4; ds++) {
            const int d = ds * 16 + l16;
            out[((size_t)(b * Cch + h * Dh + d)) * Nn + i] = Of[ds][r] * inv;
        }
    }
}

// ---------------------------------------------------------------------------
extern "C" void kernel_launch(void* const* d_in, const int* in_sizes, int n_in,
                              void* d_out, int out_size, void* d_ws, size_t ws_size,
                              hipStream_t stream)
{
    const float* x     = (const float*)d_in[0];
    const float* Wq    = (const float*)d_in[1];
    const float* bq    = (const float*)d_in[2];
    const float* Wk    = (const float*)d_in[3];
    const float* bk    = (const float*)d_in[4];
    const float* Wv    = (const float*)d_in[5];
    const float* bv    = (const float*)d_in[6];
    const float* rel_h = (const float*)d_in[7];
    const float* rel_w = (const float*)d_in[8];

    f16* ws = (f16*)d_ws;
    const size_t SZQ = (size_t)Bb * NH * Nn * Dh;    // 4 Mi elems
    f16* qt   = ws;                                  // 8 MB
    f16* kt   = ws + SZQ;                            // 8 MB
    f16* vbuf = ws + 2 * SZQ;                        // 8 MB

    gemm_qkv<<<dim3(Nn / 128, 6, Bb), 256, 0, stream>>>(
        x, Wq, Wk, Wv, bq, bk, bv, qt, kt, vbuf);
    attn_mfma<<<dim3(512), 512, 0, stream>>>(
        qt, kt, rel_h, rel_w, vbuf, (float*)d_out);
}

// Round 8
// 157.228 us; speedup vs baseline: 1.1548x; 1.0546x over previous
//
#include <hip/hip_runtime.h>

// B=16, C=256, HEADS=4, d=64, N=W*H=1024
constexpr int Bb  = 16;
constexpr int Cch = 256;
constexpr int NH  = 4;
constexpr int Dh  = 64;
constexpr int Nn  = 1024;

typedef _Float16 f16;
typedef __attribute__((ext_vector_type(8))) _Float16 f16x8;
typedef __attribute__((ext_vector_type(4))) _Float16 f16x4;
typedef __attribute__((ext_vector_type(4))) float    f32x4;

// ---------------------------------------------------------------------------
// QKV projection GEMM, fp16 MFMA + rel_t slice.
// ROUND 8: y==6 slice (128 blocks) produces rel_t (prep_rel merged into this
// grid -> no third kernel). y<6 path unchanged from R7:
//  - W chunk [128 o][32 c]: float4 loads, in-register f16 cast, direct Wt.
//  - x chunk loaded directly transposed (per-lane 8 dword column gather;
//    lanes read consecutive n -> coalesced 256B/instruction).
//  - 2 barriers/step, LDS 20 KB.
//  - x-panel sharing: blocks of one (b,bx) have equal linear-id mod 8
//    -> same XCD -> x fetched ~once from HBM.
// grid = (8, 7, 16), block = 256.
// ---------------------------------------------------------------------------
__global__ __launch_bounds__(256) void gemm_qkv(
    const float* __restrict__ x,
    const float* __restrict__ Wq, const float* __restrict__ Wk,
    const float* __restrict__ Wv,
    const float* __restrict__ bq, const float* __restrict__ bk,
    const float* __restrict__ bv,
    const float* __restrict__ rel_h, const float* __restrict__ rel_w,
    f16* __restrict__ qt, f16* __restrict__ kt, f16* __restrict__ vb,
    f16* __restrict__ rel_t)
{
    const int bx   = blockIdx.x;
    const int y    = blockIdx.y;
    const int b    = blockIdx.z;

    if (y == 6) {
        // rel_t[h][n][d] = f16(rel_h[h][d][n&31] + rel_w[h][d][n>>5])
        // 128 blocks x 256 thr x 8 elems = 262144
        const int k    = b * 8 + bx;                    // 0..127
        const int idx0 = k * 2048 + threadIdx.x * 8;
        const int d0 = idx0 & 63;
        const int n  = (idx0 >> 6) & (Nn - 1);
        const int h  = idx0 >> 16;
        f16x8 w;
        #pragma unroll
        for (int u = 0; u < 8; u++) {
            const int hd = h * 64 + d0 + u;
            w[u] = (f16)(rel_h[hd * 32 + (n & 31)] + rel_w[hd * 32 + (n >> 5)]);
        }
        *(f16x8*)&rel_t[idx0] = w;
        return;
    }

    const int p    = y >> 1;
    const int half = y & 1;

    constexpr int ST = 40;
    __shared__ f16 Wt[128 * ST];    // [o 128][c 32]
    __shared__ f16 Xt[128 * ST];    // [n 128][c 32]

    const int t    = threadIdx.x;
    const int wave = t >> 6;
    const int lane = t & 63;
    const int l16  = lane & 15;
    const int quad = lane >> 4;
    const int wm   = wave >> 1;
    const int wsd  = wave & 1;

    const float* Wsel = (p == 0) ? Wq : (p == 1) ? Wk : Wv;

    f32x4 acc[4][4];
    #pragma unroll
    for (int mi = 0; mi < 4; mi++)
        #pragma unroll
        for (int ni = 0; ni < 4; ni++) acc[mi][ni] = (f32x4){0.f, 0.f, 0.f, 0.f};

    for (int c0 = 0; c0 < 256; c0 += 32) {
        // ---- global -> regs ----
        float4 wreg[4];
        float  xcol[2][8];
        #pragma unroll
        for (int rep = 0; rep < 4; rep++) {
            const int e  = t + rep * 256;
            const int r  = e >> 3;          // o row 0..127
            const int c4 = e & 7;           // float4 within 32-c chunk
            wreg[rep] = *(const float4*)
                &Wsel[(size_t)(half * 128 + r) * 256 + c0 + c4 * 4];
        }
        #pragma unroll
        for (int rep = 0; rep < 2; rep++) {
            const int e  = t + rep * 256;
            const int nn = e & 127;         // n within 128-tile
            const int c8 = e >> 7;          // 8-c group 0..3
            #pragma unroll
            for (int u = 0; u < 8; u++)
                xcol[rep][u] = x[((size_t)b * Cch + c0 + c8 * 8 + u) * Nn
                                 + bx * 128 + nn];
        }
        __syncthreads();   // prior MFMA reads of Wt/Xt complete

        // ---- regs -> LDS (cast) ----
        #pragma unroll
        for (int rep = 0; rep < 4; rep++) {
            const int e  = t + rep * 256;
            const int r  = e >> 3;
            const int c4 = e & 7;
            f16x4 wv;
            wv.x = (f16)wreg[rep].x; wv.y = (f16)wreg[rep].y;
            wv.z = (f16)wreg[rep].z; wv.w = (f16)wreg[rep].w;
            *(f16x4*)&Wt[r * ST + c4 * 4] = wv;
        }
        #pragma unroll
        for (int rep = 0; rep < 2; rep++) {
            const int e  = t + rep * 256;
            const int nn = e & 127;
            const int c8 = e >> 7;
            f16x8 xv;
            #pragma unroll
            for (int u = 0; u < 8; u++) xv[u] = (f16)xcol[rep][u];
            *(f16x8*)&Xt[nn * ST + c8 * 8] = xv;
        }
        __syncthreads();

        // ---- MFMA (unchanged) ----
        const f16* tf = (p < 2) ? Wt : Xt;
        const f16* ts = (p < 2) ? Xt : Wt;
        f16x8 af[4], bf[4];
        #pragma unroll
        for (int mi = 0; mi < 4; mi++)
            af[mi] = *(const f16x8*)&tf[(wm * 64 + mi * 16 + l16) * ST + quad * 8];
        #pragma unroll
        for (int ni = 0; ni < 4; ni++)
            bf[ni] = *(const f16x8*)&ts[(wsd * 64 + ni * 16 + l16) * ST + quad * 8];
        #pragma unroll
        for (int mi = 0; mi < 4; mi++)
            #pragma unroll
            for (int ni = 0; ni < 4; ni++)
                acc[mi][ni] = __builtin_amdgcn_mfma_f32_16x16x32_f16(
                    af[mi], bf[ni], acc[mi][ni], 0, 0, 0);
    }

    if (p < 2) {
        f16* yt = (p == 0) ? qt : kt;
        const float* bg = (p == 0) ? bq : bk;
        #pragma unroll
        for (int mi = 0; mi < 4; mi++) {
            const int o_in = half * 128 + wm * 64 + mi * 16 + quad * 4;
            const float4 b4 = *(const float4*)&bg[o_in];
            const int h = o_in >> 6;
            const int d = o_in & 63;
            #pragma unroll
            for (int ni = 0; ni < 4; ni++) {
                const int n = bx * 128 + wsd * 64 + ni * 16 + l16;
                f16x4 w;
                w.x = (f16)(acc[mi][ni][0] + b4.x);
                w.y = (f16)(acc[mi][ni][1] + b4.y);
                w.z = (f16)(acc[mi][ni][2] + b4.z);
                w.w = (f16)(acc[mi][ni][3] + b4.w);
                *(f16x4*)&yt[(((size_t)b * NH + h) * Nn + n) * Dh + d] = w;
            }
        }
    } else {
        #pragma unroll
        for (int ni = 0; ni < 4; ni++) {
            const int c  = half * 128 + wsd * 64 + ni * 16 + l16;
            const float bs = bv[c];
            #pragma unroll
            for (int mi = 0; mi < 4; mi++) {
                const int n = bx * 128 + wm * 64 + mi * 16 + quad * 4;
                f16x4 w;
                w.x = (f16)(acc[mi][ni][0] + bs);
                w.y = (f16)(acc[mi][ni][1] + bs);
                w.z = (f16)(acc[mi][ni][2] + bs);
                w.w = (f16)(acc[mi][ni][3] + bs);
                *(f16x4*)&vb[((size_t)b * Cch + c) * Nn + n] = w;
            }
        }
    }
}

// ---------------------------------------------------------------------------
// Flash attention, fp16 MFMA, XOR-swizzled LDS. ROUND 8: exact revert to the
// R4-passing version (reads precomputed relt; inline rel gather removed —
// it cost +6.7 us of VALU/latency inside attn). XCD-bijective mapping kept
// (FETCH 102->13.8 MB), no setprio.
// grid = (512), block = 512.
// ---------------------------------------------------------------------------
__global__ __launch_bounds__(512, 4) void attn_mfma(
    const f16* __restrict__ qt, const f16* __restrict__ kt,
    const f16* __restrict__ relt, const f16* __restrict__ vb,
    float* __restrict__ out)
{
    // XCD-bijective decode: all blocks with the same bh share an XCD
    const int bid = blockIdx.x;
    const int bh  = bid & 63;         // b*4 + h
    const int i0  = (bid >> 6) * 128;
    const int h   = bh & 3;
    const int b   = bh >> 2;

    const f16* qtb = qt  + (size_t)bh * Nn * Dh;            // [n][64]
    const f16* ktb = kt  + (size_t)bh * Nn * Dh;            // [n][64]
    const f16* rlt = relt + (size_t)h * Nn * Dh;            // [n][64]
    const f16* vbb = vb  + (size_t)(b * Cch + h * Dh) * Nn; // [d][1024]

    // XOR-swizzled tiles: elem(row, col) at row*W + ((col>>3 ^ (row&7))<<3) + (col&7)
    __shared__ f16 Qa_s[128 * 128];  // 32 KB  [i][128: q|rel]
    __shared__ f16 Ka_s[64 * 128];   // 16 KB  [j][128: k|q]
    __shared__ f16 v_s [64 * 64];    //  8 KB  [d][j]
    __shared__ f16 Pt_s[128 * 64];   // 16 KB  [i][j]

    const int t    = threadIdx.x;
    const int wave = t >> 6;         // 0..7
    const int lane = t & 63;
    const int l16  = lane & 15;
    const int quad = lane >> 4;

    // ---- stage Qa = [q | rel]: 128 rows x 128 f16, swizzled ----
    #pragma unroll
    for (int rep = 0; rep < 4; rep++) {
        const int e   = t + rep * 512;
        const int row = e >> 4;
        const int c8  = e & 15;
        const f16* src = (c8 < 8)
            ? &qtb[(size_t)(i0 + row) * Dh + c8 * 8]
            : &rlt[(size_t)(i0 + row) * Dh + (c8 - 8) * 8];
        *(f16x8*)&Qa_s[(row << 7) + ((c8 ^ (row & 7)) << 3)] = *(const f16x8*)src;
    }
    __syncthreads();

    // ---- hoist Qa A-fragments (j-invariant): 1 m-subtile x 4 k-slices ----
    f16x8 af[4];
    {
        const int row = wave * 16 + l16;
        #pragma unroll
        for (int k = 0; k < 4; k++)
            af[k] = *(const f16x8*)
                &Qa_s[(row << 7) + ((((k << 2) + quad) ^ (row & 7)) << 3)];
    }

    f16x8 ones;
    #pragma unroll
    for (int u = 0; u < 8; u++) ones[u] = (f16)1.0f;

    f32x4 Of[4], Ol;
    float m_r[4];
    Ol = (f32x4){0.f, 0.f, 0.f, 0.f};
    #pragma unroll
    for (int ds = 0; ds < 4; ds++) Of[ds] = (f32x4){0.f, 0.f, 0.f, 0.f};
    #pragma unroll
    for (int r = 0; r < 4; r++) m_r[r] = -1e30f;

    for (int j0 = 0; j0 < Nn; j0 += 64) {
        // global -> regs
        f16x8 kreg[2], vreg;
        #pragma unroll
        for (int rep = 0; rep < 2; rep++) {
            const int e   = t + rep * 512;
            const int row = e >> 4;
            const int c8  = e & 15;
            const f16* src = (c8 < 8)
                ? &ktb[(size_t)(j0 + row) * Dh + c8 * 8]
                : &qtb[(size_t)(j0 + row) * Dh + (c8 - 8) * 8];
            kreg[rep] = *(const f16x8*)src;
        }
        {
            const int row = t >> 3;
            const int c8  = t & 7;
            vreg = *(const f16x8*)&vbb[(size_t)row * Nn + j0 + c8 * 8];
        }

        __syncthreads();   // prior iter's Ka/v reads complete
        #pragma unroll
        for (int rep = 0; rep < 2; rep++) {
            const int e   = t + rep * 512;
            const int row = e >> 4;
            const int c8  = e & 15;
            *(f16x8*)&Ka_s[(row << 7) + ((c8 ^ (row & 7)) << 3)] = kreg[rep];
        }
        {
            const int row = t >> 3;
            const int c8  = t & 7;
            *(f16x8*)&v_s[(row << 6) + ((c8 ^ (row & 7)) << 3)] = vreg;
        }
        __syncthreads();

        // ---- S = Qa·Ka^T : 16 rows x 64 cols, K=128 ----
        f32x4 Sf[4];
        #pragma unroll
        for (int js = 0; js < 4; js++) Sf[js] = (f32x4){0.f, 0.f, 0.f, 0.f};
        #pragma unroll
        for (int k = 0; k < 4; k++) {
            f16x8 bb[4];
            #pragma unroll
            for (int js = 0; js < 4; js++) {
                const int row = js * 16 + l16;
                bb[js] = *(const f16x8*)
                    &Ka_s[(row << 7) + ((((k << 2) + quad) ^ (row & 7)) << 3)];
            }
            #pragma unroll
            for (int js = 0; js < 4; js++)
                Sf[js] = __builtin_amdgcn_mfma_f32_16x16x32_f16(
                    af[k], bb[js], Sf[js], 0, 0, 0);
        }

        // ---- online softmax (max tree only; sums via MFMA ones) ----
        #pragma unroll
        for (int r = 0; r < 4; r++) {
            float tm = fmaxf(fmaxf(Sf[0][r], Sf[1][r]),
                             fmaxf(Sf[2][r], Sf[3][r]));
            tm = fmaxf(tm, __shfl_xor(tm, 1));
            tm = fmaxf(tm, __shfl_xor(tm, 2));
            tm = fmaxf(tm, __shfl_xor(tm, 4));
            tm = fmaxf(tm, __shfl_xor(tm, 8));
            const float mnew  = fmaxf(m_r[r], tm);
            const float alpha = __expf(m_r[r] - mnew);
            m_r[r] = mnew;

            const int row = wave * 16 + quad * 4 + r;
            const int rx  = row & 7;
            #pragma unroll
            for (int js = 0; js < 4; js++) {
                const float p = __expf(Sf[js][r] - mnew);
                const int col = js * 16 + l16;
                Pt_s[(row << 6) + (((col >> 3) ^ rx) << 3) + (col & 7)] = (f16)p;
            }
            #pragma unroll
            for (int ds = 0; ds < 4; ds++) Of[ds][r] *= alpha;
            Ol[r] *= alpha;
        }
        // Pt rows are wave-private: in-wave LDS ordering, no barrier

        // ---- O += P·V^T (K=64); l += P·1 ----
        #pragma unroll
        for (int ks = 0; ks < 2; ks++) {
            const int prow = wave * 16 + l16;
            f16x8 pa = *(const f16x8*)
                &Pt_s[(prow << 6) + ((((ks << 2) + quad) ^ (prow & 7)) << 3)];
            #pragma unroll
            for (int ds = 0; ds < 4; ds++) {
                const int vrow = ds * 16 + l16;
                f16x8 vv = *(const f16x8*)
                    &v_s[(vrow << 6) + ((((ks << 2) + quad) ^ (vrow & 7)) << 3)];
                Of[ds] = __builtin_amdgcn_mfma_f32_16x16x32_f16(
                    pa, vv, Of[ds], 0, 0, 0);
            }
            Ol = __builtin_amdgcn_mfma_f32_16x16x32_f16(
                pa, ones, Ol, 0, 0, 0);
        }
    }

    // ---- epilogue ----
    #pragma unroll
    for (int r = 0; r < 4; r++) {
        const float inv = 1.0f / Ol[r];
        const int i = i0 + wave * 16 + quad * 4 + r;
        #pragma unroll
        for (int ds = 0; ds < 4; ds++) {
            const int d = ds * 16 + l16;
            out[((size_t)(b * Cch + h * Dh + d)) * Nn + i] = Of[ds][r] * inv;
        }
    }
}

// ---------------------------------------------------------------------------
extern "C" void kernel_launch(void* const* d_in, const int* in_sizes, int n_in,
                              void* d_out, int out_size, void* d_ws, size_t ws_size,
                              hipStream_t stream)
{
    const float* x     = (const float*)d_in[0];
    const float* Wq    = (const float*)d_in[1];
    const float* bq    = (const float*)d_in[2];
    const float* Wk    = (const float*)d_in[3];
    const float* bk    = (const float*)d_in[4];
    const float* Wv    = (const float*)d_in[5];
    const float* bv    = (const float*)d_in[6];
    const float* rel_h = (const float*)d_in[7];
    const float* rel_w = (const float*)d_in[8];

    f16* ws = (f16*)d_ws;
    const size_t SZQ = (size_t)Bb * NH * Nn * Dh;    // 4 Mi elems
    f16* qt   = ws;                                  // 8 MB
    f16* kt   = ws + SZQ;                            // 8 MB
    f16* vbuf = ws + 2 * SZQ;                        // 8 MB
    f16* relt = ws + 3 * SZQ;                        // 0.5 MB

    gemm_qkv<<<dim3(Nn / 128, 7, Bb), 256, 0, stream>>>(
        x, Wq, Wk, Wv, bq, bk, bv, rel_h, rel_w, qt, kt, vbuf, relt);
    attn_mfma<<<dim3(512), 512, 0, stream>>>(
        qt, kt, relt, vbuf, (float*)d_out);
}